// Round 1
// baseline (174.692 us; speedup 1.0000x reference)
//
#include <hip/hip_runtime.h>
#include <cstddef>
#include <cstdint>

#define BATCH 128
#define NF 7

__device__ __forceinline__ float fast_silu(float a) {
    // a * sigmoid(a) = a * rcp(1 + exp2(-a*log2e))
    float e = __builtin_amdgcn_exp2f(a * -1.442695041f);
    return a * __builtin_amdgcn_rcpf(1.0f + e);
}

// feats layout: out[i][f][b], f in {x, sin x, sin 2x, sin 4x, cos x, cos 2x, cos 4x}
__global__ void feats_kernel(const float* __restrict__ in, float* __restrict__ out,
                             int din, int do_elu) {
    int t = blockIdx.x * blockDim.x + threadIdx.x;
    if (t >= din * BATCH) return;
    int b = t & (BATCH - 1);
    int i = t >> 7;
    float v = in[b * din + i];
    if (do_elu) v = (v > 0.0f) ? v : (__builtin_amdgcn_exp2f(v * 1.442695041f) - 1.0f);
    float s1, c1, s2, c2, s4, c4;
    sincosf(v, &s1, &c1);
    sincosf(2.0f * v, &s2, &c2);
    sincosf(4.0f * v, &s4, &c4);
    float* o = out + (size_t)i * (NF * BATCH) + b;
    o[0 * BATCH] = v;
    o[1 * BATCH] = s1;
    o[2 * BATCH] = s2;
    o[3 * BATCH] = s4;
    o[4 * BATCH] = c1;
    o[5 * BATCH] = c2;
    o[6 * BATCH] = c4;
}

// One wave owns one (i, j) weight block at a time; lane l covers batch rows l and l+64.
// Partial sums over the wave's i-slice are block-reduced and atomically added into out[b][j].
template <int DIN, int DOUT, int CHUNK>
__global__ __launch_bounds__(256, 4) void kan_kernel(
    const float* __restrict__ fx,   // [DIN][NF][BATCH]
    const float* __restrict__ W1,   // [DIN][DOUT][32][7]
    const float* __restrict__ W2,   // [DIN][DOUT][32]
    const float* __restrict__ B1,   // [DIN][DOUT][32]
    const float* __restrict__ B2,   // [DIN][DOUT]
    float* __restrict__ out)        // [BATCH][DOUT], pre-zeroed, atomic accum
{
    __shared__ float smem[4 * 320];     // per-wave: 32*8 padded W1 + 32*2 interleaved {B1,W2}
    __shared__ float redbuf[4 * 128];
    const int j    = blockIdx.x;
    const int tid  = threadIdx.x;
    const int w    = tid >> 6;
    const int lane = tid & 63;
    const int wb   = w * 320;
    const int i0   = blockIdx.y * CHUNK;

    float tot0 = 0.0f, tot1 = 0.0f;

    for (int t = 0; t < CHUNK / 4; ++t) {
        const int i = i0 + t * 4 + w;
        // ---- stage weights for (i, j) into this wave's LDS region ----
        const float* w1p = W1 + ((size_t)i * DOUT + j) * 224;
        if (lane < 56) {
            const float4 v = *(const float4*)(w1p + lane * 4);
            const float* vp = (const float*)&v;
            #pragma unroll
            for (int q = 0; q < 4; ++q) {
                int e = lane * 4 + q;
                smem[wb + (e / 7) * 8 + (e % 7)] = vp[q];   // pad 7 -> 8 per h
            }
        }
        const float* b1p = B1 + ((size_t)i * DOUT + j) * 32;
        const float* w2p = W2 + ((size_t)i * DOUT + j) * 32;
        if (lane < 32) smem[wb + 256 + 2 * lane]              = b1p[lane];
        else           smem[wb + 256 + 2 * (lane - 32) + 1]   = w2p[lane - 32];
        __syncthreads();

        // ---- per-lane feats (2 batch rows) ----
        const float* fp = fx + (size_t)i * (NF * BATCH) + lane;
        float f0[NF], f1[NF];
        #pragma unroll
        for (int f = 0; f < NF; ++f) { f0[f] = fp[f * BATCH]; f1[f] = fp[f * BATCH + 64]; }

        float o0 = 0.0f, o1 = 0.0f;
        #pragma unroll 8
        for (int h = 0; h < 32; ++h) {
            float b1v = smem[wb + 256 + 2 * h];
            float w2v = smem[wb + 256 + 2 * h + 1];
            float a0 = b1v, a1 = b1v;
            #pragma unroll
            for (int f = 0; f < NF; ++f) {
                float ww = smem[wb + h * 8 + f];   // broadcast; vectorizes to ds_read_b128/b64/b32
                a0 = fmaf(f0[f], ww, a0);
                a1 = fmaf(f1[f], ww, a1);
            }
            o0 = fmaf(fast_silu(a0), w2v, o0);
            o1 = fmaf(fast_silu(a1), w2v, o1);
        }
        float b2v = B2[(size_t)i * DOUT + j];
        tot0 += o0 + b2v;
        tot1 += o1 + b2v;
        __syncthreads();   // region reuse next iteration (cheap, waves are in lockstep)
    }

    // ---- block-level reduce over the 4 waves, then one atomic per (b, j) ----
    redbuf[w * 128 + lane]      = tot0;
    redbuf[w * 128 + 64 + lane] = tot1;
    __syncthreads();
    if (tid < 128) {
        float s = redbuf[tid] + redbuf[128 + tid] + redbuf[256 + tid] + redbuf[384 + tid];
        atomicAdd(&out[(size_t)tid * DOUT + j], s);
    }
}

// GLU gate + residual + BatchNorm(batch axis), one block per output column j.
__device__ __forceinline__ int shidx(int k, int b) { return (k << 7) + ((b + k) & 127); }

__global__ __launch_bounds__(128) void glu_bn_kernel(
    const float* __restrict__ h2,     // [BATCH][128]
    const float* __restrict__ resid,  // [BATCH][128]
    const float* __restrict__ g1w, const float* __restrict__ g1b,
    const float* __restrict__ g2w, const float* __restrict__ g2b,
    const float* __restrict__ bnw, const float* __restrict__ bnb,
    float* __restrict__ out)          // [BATCH][128]
{
    __shared__ float sh[128 * 128];   // swizzled h2 tile, 64 KiB
    const int j   = blockIdx.x;
    const int tid = threadIdx.x;      // = batch row b

    // load h2 with coalesced global reads, conflict-free swizzled LDS writes
    for (int b2 = 0; b2 < 128; ++b2)
        sh[shidx(tid, b2)] = h2[(size_t)b2 * 128 + tid];
    __syncthreads();

    const float* g1r = g1w + (size_t)j * 128;   // wave-uniform -> scalar loads
    const float* g2r = g2w + (size_t)j * 128;
    float d1 = g1b[j], d2 = g2b[j];
    for (int k = 0; k < 128; ++k) {
        float hv = sh[shidx(k, tid)];
        d1 = fmaf(hv, g1r[k], d1);
        d2 = fmaf(hv, g2r[k], d2);
    }
    float sg = __builtin_amdgcn_rcpf(1.0f + __builtin_amdgcn_exp2f(d1 * -1.442695041f));
    float v  = sg * d2 + resid[(size_t)tid * 128 + j];

    // batch mean/var (biased) over the 128 rows
    float s = v, ss = v * v;
    #pragma unroll
    for (int m = 1; m < 64; m <<= 1) {
        s  += __shfl_xor(s,  m, 64);
        ss += __shfl_xor(ss, m, 64);
    }
    __syncthreads();                 // everyone done reading sh -> reuse
    if ((tid & 63) == 0) { sh[(tid >> 6) * 2] = s; sh[(tid >> 6) * 2 + 1] = ss; }
    __syncthreads();
    s  = sh[0] + sh[2];
    ss = sh[1] + sh[3];
    float mean = s * (1.0f / 128.0f);
    float var  = ss * (1.0f / 128.0f) - mean * mean;
    out[(size_t)tid * 128 + j] = (v - mean) * rsqrtf(var + 1e-5f) * bnw[j] + bnb[j];
}

extern "C" void kernel_launch(void* const* d_in, const int* in_sizes, int n_in,
                              void* d_out, int out_size, void* d_ws, size_t ws_size,
                              hipStream_t stream) {
    const float* x      = (const float*)d_in[0];
    const float* fc1_W1 = (const float*)d_in[1];
    const float* fc1_W2 = (const float*)d_in[2];
    const float* fc1_B1 = (const float*)d_in[3];
    const float* fc1_B2 = (const float*)d_in[4];
    const float* fc2_W1 = (const float*)d_in[5];
    const float* fc2_W2 = (const float*)d_in[6];
    const float* fc2_B1 = (const float*)d_in[7];
    const float* fc2_B2 = (const float*)d_in[8];
    const float* sk_W1  = (const float*)d_in[9];
    const float* sk_W2  = (const float*)d_in[10];
    const float* sk_B1  = (const float*)d_in[11];
    const float* sk_B2  = (const float*)d_in[12];
    const float* g1w    = (const float*)d_in[13];
    const float* g1b    = (const float*)d_in[14];
    const float* g2w    = (const float*)d_in[15];
    const float* g2b    = (const float*)d_in[16];
    const float* bnw    = (const float*)d_in[17];
    const float* bnb    = (const float*)d_in[18];
    float* out = (float*)d_out;

    float* ws    = (float*)d_ws;
    float* h1    = ws;                    // 128*256
    float* h2    = h1 + 128 * 256;        // 128*128
    float* resid = h2 + 128 * 128;        // 128*128
    float* fx    = resid + 128 * 128;     // 128*7*128
    float* fh    = fx + 128 * NF * 128;   // 256*7*128

    // zero the three atomic accumulators (h1 | h2 | resid are contiguous)
    hipMemsetAsync(h1, 0, (size_t)(128 * 256 + 2 * 128 * 128) * sizeof(float), stream);

    feats_kernel<<<dim3((128 * BATCH) / 256), 256, 0, stream>>>(x, fx, 128, 0);

    kan_kernel<128, 256, 32><<<dim3(256, 4), 256, 0, stream>>>(
        fx, fc1_W1, fc1_W2, fc1_B1, fc1_B2, h1);
    kan_kernel<128, 128, 16><<<dim3(128, 8), 256, 0, stream>>>(
        fx, sk_W1, sk_W2, sk_B1, sk_B2, resid);

    feats_kernel<<<dim3((256 * BATCH) / 256), 256, 0, stream>>>(h1, fh, 256, 1);

    kan_kernel<256, 128, 32><<<dim3(128, 8), 256, 0, stream>>>(
        fh, fc2_W1, fc2_W2, fc2_B1, fc2_B2, h2);

    glu_bn_kernel<<<dim3(128), 128, 0, stream>>>(
        h2, resid, g1w, g1b, g2w, g2b, bnw, bnb, out);
}

// Round 2
// 160.314 us; speedup vs baseline: 1.0897x; 1.0897x over previous
//
#include <hip/hip_runtime.h>
#include <cstddef>
#include <cstdint>

#define BATCH 128
#define NF 7

typedef float v2f __attribute__((ext_vector_type(2)));

__device__ __forceinline__ v2f vfma(v2f a, float b, v2f c) {
#if __has_builtin(__builtin_elementwise_fma)
    return __builtin_elementwise_fma(a, (v2f)(b), c);
#else
    v2f r; r.x = fmaf(a.x, b, c.x); r.y = fmaf(a.y, b, c.y); return r;
#endif
}

__device__ __forceinline__ v2f silu2(v2f a) {
    v2f t = a * -1.442695041f;                 // pk_mul
    v2f e;
    e.x = __builtin_amdgcn_exp2f(t.x);
    e.y = __builtin_amdgcn_exp2f(t.y);
    v2f d = e + 1.0f;                          // pk_add
    v2f r;
    r.x = __builtin_amdgcn_rcpf(d.x);
    r.y = __builtin_amdgcn_rcpf(d.y);
    return a * r;                              // pk_mul
}

// feats layout: out[i][f][lane] as float2 {row b, row b+64}, f in {x, sin x, sin 2x, sin 4x, cos x, cos 2x, cos 4x}
__global__ void feats_kernel(const float* __restrict__ in, float* __restrict__ out,
                             int din, int do_elu) {
    int t = blockIdx.x * blockDim.x + threadIdx.x;
    if (t >= din * BATCH) return;
    int b = t & (BATCH - 1);
    int i = t >> 7;
    float v = in[b * din + i];
    if (do_elu) v = (v > 0.0f) ? v : (__builtin_amdgcn_exp2f(v * 1.442695041f) - 1.0f);
    float s1, c1, s2, c2, s4, c4;
    sincosf(v, &s1, &c1);
    sincosf(2.0f * v, &s2, &c2);
    sincosf(4.0f * v, &s4, &c4);
    float* o = out + (size_t)i * (NF * 128) + (b & 63) * 2 + (b >> 6);
    o[0 * 128] = v;
    o[1 * 128] = s1;
    o[2 * 128] = s2;
    o[3 * 128] = s4;
    o[4 * 128] = c1;
    o[5 * 128] = c2;
    o[6 * 128] = c4;
}

// One wave owns one (i, j) weight block at a time; lane l covers batch rows l and l+64
// packed as a float2 so the backend emits v_pk_fma_f32. No in-loop barriers: each wave
// has a private LDS region; intra-wave LDS ordering is handled by compiler waitcnts.
template <int DIN, int DOUT, int CHUNK>
__global__ __launch_bounds__(256, 8) void kan_kernel(
    const float* __restrict__ fx,   // [DIN][NF][64] of float2 pairs
    const float* __restrict__ W1,   // [DIN][DOUT][32][7]
    const float* __restrict__ W2,   // [DIN][DOUT][32]
    const float* __restrict__ B1,   // [DIN][DOUT][32]
    const float* __restrict__ B2,   // [DIN][DOUT]
    float* __restrict__ out)        // [BATCH][DOUT], pre-zeroed, atomic accum
{
    __shared__ float smem[4 * 320];     // per-wave: 32 rows of {w0..w6, b1} + 32 w2
    __shared__ float redbuf[4 * 128];
    const int j    = blockIdx.x;
    const int tid  = threadIdx.x;
    const int w    = tid >> 6;
    const int lane = tid & 63;
    const int wb   = w * 320;
    const int i0   = blockIdx.y * CHUNK;

    v2f tot = (v2f)(0.0f);

    for (int t = 0; t < CHUNK / 4; ++t) {
        const int i = i0 + t * 4 + w;
        // ---- stage weights for (i, j) into this wave's private LDS region ----
        const float* w1p = W1 + ((size_t)i * DOUT + j) * 224;
        if (lane < 56) {
            const float4 v = *(const float4*)(w1p + lane * 4);
            const float* vp = (const float*)&v;
            #pragma unroll
            for (int q = 0; q < 4; ++q) {
                int e = lane * 4 + q;
                smem[wb + (e / 7) * 8 + (e % 7)] = vp[q];   // row h: {w0..w6, b1}
            }
        }
        const float* b1p = B1 + ((size_t)i * DOUT + j) * 32;
        const float* w2p = W2 + ((size_t)i * DOUT + j) * 32;
        if (lane < 32) smem[wb + lane * 8 + 7]       = b1p[lane];
        else           smem[wb + 256 + (lane - 32)]  = w2p[lane - 32];

        // ---- per-lane feats: 2 batch rows packed as float2 ----
        const float* fp = fx + (size_t)i * (NF * 128) + lane * 2;
        v2f f[NF];
        #pragma unroll
        for (int ff = 0; ff < NF; ++ff) f[ff] = *(const v2f*)(fp + ff * 128);

        v2f o = (v2f)(0.0f);
        #pragma unroll 2
        for (int h4 = 0; h4 < 8; ++h4) {
            const float4 w2q = *(const float4*)&smem[wb + 256 + h4 * 4];
            const float* w2s = (const float*)&w2q;
            #pragma unroll
            for (int hh = 0; hh < 4; ++hh) {
                const int h = h4 * 4 + hh;
                const float4 L  = *(const float4*)&smem[wb + h * 8];
                const float4 Hq = *(const float4*)&smem[wb + h * 8 + 4];
                v2f a = (v2f)(Hq.w);               // b1
                a = vfma(f[0], L.x,  a);
                a = vfma(f[1], L.y,  a);
                a = vfma(f[2], L.z,  a);
                a = vfma(f[3], L.w,  a);
                a = vfma(f[4], Hq.x, a);
                a = vfma(f[5], Hq.y, a);
                a = vfma(f[6], Hq.z, a);
                o = vfma(silu2(a), w2s[hh], o);
            }
        }
        float b2v = B2[(size_t)i * DOUT + j];
        tot += o + b2v;
    }

    // ---- block-level reduce over the 4 waves, then one atomic per (b, j) ----
    redbuf[w * 128 + lane]      = tot.x;
    redbuf[w * 128 + 64 + lane] = tot.y;
    __syncthreads();
    if (tid < 128) {
        float s = redbuf[tid] + redbuf[128 + tid] + redbuf[256 + tid] + redbuf[384 + tid];
        atomicAdd(&out[(size_t)tid * DOUT + j], s);
    }
}

// GLU gate + residual + BatchNorm(batch axis), one block per output column j.
__device__ __forceinline__ int shidx(int k, int b) { return (k << 7) + ((b + k) & 127); }

__global__ __launch_bounds__(128) void glu_bn_kernel(
    const float* __restrict__ h2,     // [BATCH][128]
    const float* __restrict__ resid,  // [BATCH][128]
    const float* __restrict__ g1w, const float* __restrict__ g1b,
    const float* __restrict__ g2w, const float* __restrict__ g2b,
    const float* __restrict__ bnw, const float* __restrict__ bnb,
    float* __restrict__ out)          // [BATCH][128]
{
    __shared__ float sh[128 * 128];   // swizzled h2 tile, 64 KiB
    const int j   = blockIdx.x;
    const int tid = threadIdx.x;      // = batch row b

    for (int b2 = 0; b2 < 128; ++b2)
        sh[shidx(tid, b2)] = h2[(size_t)b2 * 128 + tid];
    __syncthreads();

    const float* g1r = g1w + (size_t)j * 128;
    const float* g2r = g2w + (size_t)j * 128;
    float d1 = g1b[j], d2 = g2b[j];
    for (int k = 0; k < 128; ++k) {
        float hv = sh[shidx(k, tid)];
        d1 = fmaf(hv, g1r[k], d1);
        d2 = fmaf(hv, g2r[k], d2);
    }
    float sg = __builtin_amdgcn_rcpf(1.0f + __builtin_amdgcn_exp2f(d1 * -1.442695041f));
    float v  = sg * d2 + resid[(size_t)tid * 128 + j];

    float s = v, ss = v * v;
    #pragma unroll
    for (int m = 1; m < 64; m <<= 1) {
        s  += __shfl_xor(s,  m, 64);
        ss += __shfl_xor(ss, m, 64);
    }
    __syncthreads();
    if ((tid & 63) == 0) { sh[(tid >> 6) * 2] = s; sh[(tid >> 6) * 2 + 1] = ss; }
    __syncthreads();
    s  = sh[0] + sh[2];
    ss = sh[1] + sh[3];
    float mean = s * (1.0f / 128.0f);
    float var  = ss * (1.0f / 128.0f) - mean * mean;
    out[(size_t)tid * 128 + j] = (v - mean) * rsqrtf(var + 1e-5f) * bnw[j] + bnb[j];
}

extern "C" void kernel_launch(void* const* d_in, const int* in_sizes, int n_in,
                              void* d_out, int out_size, void* d_ws, size_t ws_size,
                              hipStream_t stream) {
    const float* x      = (const float*)d_in[0];
    const float* fc1_W1 = (const float*)d_in[1];
    const float* fc1_W2 = (const float*)d_in[2];
    const float* fc1_B1 = (const float*)d_in[3];
    const float* fc1_B2 = (const float*)d_in[4];
    const float* fc2_W1 = (const float*)d_in[5];
    const float* fc2_W2 = (const float*)d_in[6];
    const float* fc2_B1 = (const float*)d_in[7];
    const float* fc2_B2 = (const float*)d_in[8];
    const float* sk_W1  = (const float*)d_in[9];
    const float* sk_W2  = (const float*)d_in[10];
    const float* sk_B1  = (const float*)d_in[11];
    const float* sk_B2  = (const float*)d_in[12];
    const float* g1w    = (const float*)d_in[13];
    const float* g1b    = (const float*)d_in[14];
    const float* g2w    = (const float*)d_in[15];
    const float* g2b    = (const float*)d_in[16];
    const float* bnw    = (const float*)d_in[17];
    const float* bnb    = (const float*)d_in[18];
    float* out = (float*)d_out;

    float* ws    = (float*)d_ws;
    float* h1    = ws;                    // 128*256
    float* h2    = h1 + 128 * 256;        // 128*128
    float* resid = h2 + 128 * 128;        // 128*128
    float* fx    = resid + 128 * 128;     // 128*7*128
    float* fh    = fx + 128 * NF * 128;   // 256*7*128

    hipMemsetAsync(h1, 0, (size_t)(128 * 256 + 2 * 128 * 128) * sizeof(float), stream);

    feats_kernel<<<dim3((128 * BATCH) / 256), 256, 0, stream>>>(x, fx, 128, 0);

    kan_kernel<128, 256, 16><<<dim3(256, 8), 256, 0, stream>>>(
        fx, fc1_W1, fc1_W2, fc1_B1, fc1_B2, h1);
    kan_kernel<128, 128, 8><<<dim3(128, 16), 256, 0, stream>>>(
        fx, sk_W1, sk_W2, sk_B1, sk_B2, resid);

    feats_kernel<<<dim3((256 * BATCH) / 256), 256, 0, stream>>>(h1, fh, 256, 1);

    kan_kernel<256, 128, 16><<<dim3(128, 16), 256, 0, stream>>>(
        fh, fc2_W1, fc2_W2, fc2_B1, fc2_B2, h2);

    glu_bn_kernel<<<dim3(128), 128, 0, stream>>>(
        h2, resid, g1w, g1b, g2w, g2b, bnw, bnb, out);
}